// Round 12
// baseline (299.004 us; speedup 1.0000x reference)
//
#include <hip/hip_runtime.h>
#include <math.h>

#define WSZ 11
#define RB 144               // output rows per block; 2160/144 = 15

typedef float f32x4 __attribute__((ext_vector_type(4)));
typedef unsigned int u32;
typedef u32 u32x4 __attribute__((ext_vector_type(4)));
typedef _Float16 f16;
typedef _Float16 f16x2v __attribute__((ext_vector_type(2)));
typedef _Float16 f16x8 __attribute__((ext_vector_type(8)));

struct W11 { float w[WSZ]; };

__device__ inline u32 packpair(float a, float b) {
    f16x2v v; v[0] = (f16)a; v[1] = (f16)b;
    return __builtin_bit_cast(u32, v);
}

// R19: conv on the MATRIX pipe. R11-R18: eight structural variants, identical
// per-px math, all pinned at VALU 44-53%; only instruction-count cuts ever
// moved dur (pk-heavy wave64 stream ~4cyc/inst -> VALU is the saturated pipe,
// MfmaUtil=0 throughout). So: 11-tap conv = banded-Toeplitz matmul.
//   h: D[m][n] = sum_k in[m][x0-5+k] * w[k-n]   (A=data, B=weights)
//   v: D[o][x] = sum_k w[k-o] * H[k][x]         (A=weights, B=H)
// Weight A-frag == weight B-frag per-lane (one shared hi/lo pair). Data f16
// RNE (unbiased 2^-11), weights split hi+lo (exact 2^-22): 2 MFMAs/conv/chan.
// K-order inside fragments cancels between A and B, so only the documented
// C/D map (col=lane&15, row=(lane>>4)*4+reg, m89-verified) must be right.
// h-D (lane = 4 consecutive rows at one col) writes the column-major f16
// H-buffer naturally; v-B reads one b128/chan. Circular 32-slot buffer
// (slot = (rowoff+5)&31) absorbs rolling halo with a SINGLE weight set.
// One wave per block: 16 cols x 144 rows, 4KB LDS, no inter-wave lockstep.
// (R11 rerun: R10 bench died on container infra before compiling; audit
// found no defects; kernel unchanged.)
__global__ __launch_bounds__(64, 4) void ssim_l1_kernel(
    const float* __restrict__ pred, const float* __restrict__ targ,
    W11 wt, float2* __restrict__ partials)
{
    constexpr int H = 2160, W = 3840;
    __shared__ u32x4 Hbuf4[4][16][4];   // [chan][col][quad of 4 u32] = 4 KB

    const int bx = blockIdx.x, c = blockIdx.z;
    const int x0   = bx * 16;
    const int base = blockIdx.y * RB;
    const size_t plane = (size_t)H * W;
    const float* p = pred + (size_t)c * plane;
    const float* t = targ + (size_t)c * plane;

    const int l   = threadIdx.x;        // 0..63 (one wave)
    const int xl  = l & 15;             // A/B non-k index; D col
    const int g   = l >> 4;             // k-chunk (8 elems)
    const int swz = (xl & 3) << 2;      // quad-granule XOR (bank spread)
    u32* Hw = (u32*)Hbuf4;

    float lssim = 0.f, ll1 = 0.f;
    const float C1v = 0.0001f, C2v = 0.0009f;
    const bool xfast = (bx >= 1) && (bx <= (W / 16) - 3);
    const f32x4 z4 = {0.f, 0.f, 0.f, 0.f};

    // ---- shared weight fragment: lane elem j holds w[8g+j - xl] (0 outside)
    f16x8 Whi, Wlo;
    #pragma unroll
    for (int j = 0; j < 8; ++j) {
        const int idx = 8 * g + j - xl;
        float wv = 0.f;
        #pragma unroll
        for (int tI = 0; tI < WSZ; ++tI) wv = (idx == tI) ? wt.w[tI] : wv;
        const f16 hi = (f16)wv;
        Whi[j] = hi;
        Wlo[j] = (f16)(wv - (float)hi);
    }

    // ---- zero slots 26..31 (words 13..15): read by v s=0 with W=0 there
    #pragma unroll
    for (int wq = 13; wq <= 15; ++wq)
        Hw[(g * 16 + xl) * 16 + (wq ^ swz)] = 0u;
    __syncthreads();

    f32x4 hS, hD, hQs, hQd;

    // ---- Phase L: load 16 rows, prep s/d/s^2/d^2, f16 A-frags, 8 h-MFMAs
    auto phaseL = [&](const int gy0, const int mlo, const int mhi) {
        const int gy = gy0 + xl;                 // A-row m = xl
        const bool rowok = (gy >= 0) && (gy < H);
        float pe[12], te[12];
        if (rowok && xfast) {
            const f32x4* p4 = (const f32x4*)(p + (size_t)gy * W + (x0 + 8 * g - 8));
            const f32x4* t4 = (const f32x4*)(t + (size_t)gy * W + (x0 + 8 * g - 8));
            #pragma unroll
            for (int i = 0; i < 3; ++i) {
                const f32x4 a = p4[i], b = t4[i];
                #pragma unroll
                for (int q = 0; q < 4; ++q) { pe[4*i+q] = a[q]; te[4*i+q] = b[q]; }
            }
        } else if (rowok) {
            const size_t ro = (size_t)gy * W;
            #pragma unroll
            for (int e = 0; e < 12; ++e) {
                const int gx = x0 + 8 * g - 8 + e;
                const bool ok = (gx >= 0) && (gx < W);
                pe[e] = ok ? p[ro + gx] : 0.f;
                te[e] = ok ? t[ro + gx] : 0.f;
            }
        } else {
            #pragma unroll
            for (int e = 0; e < 12; ++e) { pe[e] = 0.f; te[e] = 0.f; }
        }
        // used elems 3..10: cols x0 + 8g + j - 5
        float sv[8], dv[8];
        #pragma unroll
        for (int j = 0; j < 8; ++j) {
            sv[j] = pe[j + 3] + te[j + 3];
            dv[j] = pe[j + 3] - te[j + 3];
        }
        // L1: owned cols per g: j in [5,7] g0 / [0,7] g1 / [0,4] g2 / none g3
        {
            float s1 = 0.f, s2 = 0.f;
            #pragma unroll
            for (int j = 0; j < 5; ++j) s1 += fabsf(dv[j]);
            #pragma unroll
            for (int j = 5; j < 8; ++j) s2 += fabsf(dv[j]);
            const float own = (g == 0) ? s2 : (g == 1) ? (s1 + s2)
                            : (g == 2) ? s1 : 0.f;
            if (xl >= mlo && xl <= mhi) ll1 += own;   // row ownership
        }
        f16x8 fS, fD, fQs, fQd;
        #pragma unroll
        for (int j = 0; j < 8; ++j) {
            fS[j]  = (f16)sv[j];
            fD[j]  = (f16)dv[j];
            fQs[j] = (f16)(sv[j] * sv[j]);
            fQd[j] = (f16)(dv[j] * dv[j]);
        }
        hS  = __builtin_amdgcn_mfma_f32_16x16x32_f16(fS,  Whi, z4, 0, 0, 0);
        hS  = __builtin_amdgcn_mfma_f32_16x16x32_f16(fS,  Wlo, hS, 0, 0, 0);
        hD  = __builtin_amdgcn_mfma_f32_16x16x32_f16(fD,  Whi, z4, 0, 0, 0);
        hD  = __builtin_amdgcn_mfma_f32_16x16x32_f16(fD,  Wlo, hD, 0, 0, 0);
        hQs = __builtin_amdgcn_mfma_f32_16x16x32_f16(fQs, Whi, z4, 0, 0, 0);
        hQs = __builtin_amdgcn_mfma_f32_16x16x32_f16(fQs, Wlo, hQs, 0, 0, 0);
        hQd = __builtin_amdgcn_mfma_f32_16x16x32_f16(fQd, Whi, z4, 0, 0, 0);
        hQd = __builtin_amdgcn_mfma_f32_16x16x32_f16(fQd, Wlo, hQd, 0, 0, 0);
    };

    // ---- write h-D: lane holds rows a0+4g+r at col xl; slot words mod 16
    auto hwrite = [&](const int a0) {
        const int w0 = ((a0 >> 1) + 2 * g) & 15;
        const int w1 = (w0 + 1) & 15;
        Hw[(0 * 16 + xl) * 16 + (w0 ^ swz)] = packpair(hS[0],  hS[1]);
        Hw[(0 * 16 + xl) * 16 + (w1 ^ swz)] = packpair(hS[2],  hS[3]);
        Hw[(1 * 16 + xl) * 16 + (w0 ^ swz)] = packpair(hD[0],  hD[1]);
        Hw[(1 * 16 + xl) * 16 + (w1 ^ swz)] = packpair(hD[2],  hD[3]);
        Hw[(2 * 16 + xl) * 16 + (w0 ^ swz)] = packpair(hQs[0], hQs[1]);
        Hw[(2 * 16 + xl) * 16 + (w1 ^ swz)] = packpair(hQs[2], hQs[3]);
        Hw[(3 * 16 + xl) * 16 + (w0 ^ swz)] = packpair(hQd[0], hQd[1]);
        Hw[(3 * 16 + xl) * 16 + (w1 ^ swz)] = packpair(hQd[2], hQd[3]);
    };

    // ---- v-tile: 8 v-MFMAs + SSIM epilogue (out rows base+16s+4g+r, col xl)
    auto vphase = [&](const int s) {
        const int q = (((2 * s) + g) & 3) ^ (xl & 3);
        f16x8 hb;
        f32x4 aS, aD, aQs, aQd;
        hb = __builtin_bit_cast(f16x8, Hbuf4[0][xl][q]);
        aS = __builtin_amdgcn_mfma_f32_16x16x32_f16(Whi, hb, z4, 0, 0, 0);
        aS = __builtin_amdgcn_mfma_f32_16x16x32_f16(Wlo, hb, aS, 0, 0, 0);
        hb = __builtin_bit_cast(f16x8, Hbuf4[1][xl][q]);
        aD = __builtin_amdgcn_mfma_f32_16x16x32_f16(Whi, hb, z4, 0, 0, 0);
        aD = __builtin_amdgcn_mfma_f32_16x16x32_f16(Wlo, hb, aD, 0, 0, 0);
        hb = __builtin_bit_cast(f16x8, Hbuf4[2][xl][q]);
        aQs = __builtin_amdgcn_mfma_f32_16x16x32_f16(Whi, hb, z4, 0, 0, 0);
        aQs = __builtin_amdgcn_mfma_f32_16x16x32_f16(Wlo, hb, aQs, 0, 0, 0);
        hb = __builtin_bit_cast(f16x8, Hbuf4[3][xl][q]);
        aQd = __builtin_amdgcn_mfma_f32_16x16x32_f16(Whi, hb, z4, 0, 0, 0);
        aQd = __builtin_amdgcn_mfma_f32_16x16x32_f16(Wlo, hb, aQd, 0, 0, 0);
        #pragma unroll
        for (int r = 0; r < 4; ++r) {
            const float S = aS[r], D = aD[r];
            const float S2 = S * S, D2 = D * D;
            const float rs = aQs[r] - S2, rd = aQd[r] - D2;
            const float a  = 0.5f * (S2 - D2) + C1v;
            const float b  = 0.5f * (rs - rd) + C2v;
            const float cd = 0.5f * (S2 + D2) + C1v;
            const float dd = 0.5f * (rs + rd) + C2v;
            lssim += (a * b) * __builtin_amdgcn_rcpf(cd * dd);
        }
    };

    // ---- prologue: P1 rows base-5..+10 -> slots 0..15; P2 rows base+5..+20
    // -> slots 10..25 (rows 5..10 rewritten with identical values).
    phaseL(base - 5, 5, 15);  hwrite(0);
    phaseL(base + 5, 6, 15);  hwrite(10);
    __syncthreads();
    vphase(0);
    for (int s = 1; s <= 8; ++s) {
        // new rows base+16s+5 .. +20 -> slots (16s+10 .. 16s+25) mod 32
        phaseL(base + 16 * s + 5, 0, (s == 8) ? 10 : 15);
        __syncthreads();               // vphase(s-1) reads done before rewrite
        hwrite((16 * s + 10) & 31);
        __syncthreads();               // writes visible before vphase(s)
        vphase(s);
    }

    // ---- wave reduction -> one partial per block
    #pragma unroll
    for (int off = 32; off > 0; off >>= 1) {
        lssim += __shfl_down(lssim, off, 64);
        ll1   += __shfl_down(ll1,   off, 64);
    }
    if (l == 0) {
        const int bid = (blockIdx.z * gridDim.y + blockIdx.y) * gridDim.x + blockIdx.x;
        partials[bid] = make_float2(lssim, ll1);
    }
}

__global__ __launch_bounds__(256) void finalize_kernel(
    const float2* __restrict__ partials, int n,
    float* __restrict__ out, double invN)
{
    const int tid = threadIdx.x;
    double s = 0.0, l = 0.0;
    for (int i = tid; i < n; i += 256) {
        float2 v = partials[i];
        s += (double)v.x;
        l += (double)v.y;
    }
    #pragma unroll
    for (int off = 32; off > 0; off >>= 1) {
        s += __shfl_down(s, off, 64);
        l += __shfl_down(l, off, 64);
    }
    __shared__ double rs[4], rl[4];
    const int lane = tid & 63, wid = tid >> 6;
    if (lane == 0) { rs[wid] = s; rl[wid] = l; }
    __syncthreads();
    if (tid == 0) {
        const double st = rs[0] + rs[1] + rs[2] + rs[3];
        const double lt = rl[0] + rl[1] + rl[2] + rl[3];
        out[0] = (float)(0.8 * lt * invN + 0.2 * (1.0 - st * invN));
    }
}

extern "C" void kernel_launch(void* const* d_in, const int* in_sizes, int n_in,
                              void* d_out, int out_size, void* d_ws, size_t ws_size,
                              hipStream_t stream)
{
    const float* pred = (const float*)d_in[0];
    const float* targ = (const float*)d_in[1];
    float* out = (float*)d_out;
    float2* partials = (float2*)d_ws;

    const int C = 3, H = 2160, W = 3840;

    W11 wt;
    double g[WSZ], sg = 0.0;
    for (int i = 0; i < WSZ; ++i) {
        double d = (double)i - (WSZ / 2);
        g[i] = exp(-(d * d) / (2.0 * 1.5 * 1.5));
        sg += g[i];
    }
    for (int i = 0; i < WSZ; ++i) wt.w[i] = (float)(g[i] / sg);

    dim3 grid(W / 16, H / RB, C);   // 240 x 15 x 3 = 10800 one-wave blocks
    ssim_l1_kernel<<<grid, 64, 0, stream>>>(pred, targ, wt, partials);

    const int nblocks = (W / 16) * (H / RB) * C;
    double invN = 1.0 / ((double)C * (double)H * (double)W);
    finalize_kernel<<<1, 256, 0, stream>>>(partials, nblocks, out, invN);
}